// Round 4
// baseline (493.496 us; speedup 1.0000x reference)
//
#include <hip/hip_runtime.h>
#include <math.h>

// LSTMNextWindowPredictor, B=262144, I=13, H=64, T=5, O=13, fp32 in/out.
// R8 structure: TRANSPOSED dataflow. Per wave: 32 batch rows. Per t:
//   G^T[256 gates x 32 batch] = W_cat[256 x 96] * [x;1;h]^T
// via mfma_f32_16x16x32_f16, K=96 = {k0-63: h, k64-76: x, k77: 1 (bias col)}.
// Weights are A-fragments in LDS (40 KB = whh 32K + wx 8K) -> conflict-free
// ds_read_b128, no L2 thrash (R5-R7 read them from global: 2 GB L2 traffic,
// 85 MB/dispatch HBM misses, latency stall in front of every MFMA).
// Batch index is lane-local (D col = lane&15) -> h lives in registers;
// k-regrouping between t steps via cvt-pack + ds_bpermute (no hshm LDS).
// Bias rides the k=77 constant-1 channel -> acc init = shared ZERO quad.
// Elementwise: R6 math (scaled weights, exp2/rcp, 7 trans/element, pk-f32).
// __launch_bounds__(256,4): unified VGPR+AGPR ~128/wave pins 4 waves/SIMD;
// (256,8) in R7 forced 32 VGPRs -> catastrophic scratch spills. Don't.

#define TT 5
#define NI 13

typedef _Float16 half8 __attribute__((ext_vector_type(8)));
typedef __attribute__((ext_vector_type(4))) float f32x4;
typedef __attribute__((ext_vector_type(2))) float f32x2;

// ws byte offsets
#define WHH_OFF 0        // 16384 halves [tile16][kt2][lane64][j8] (32 KB)
#define WX_OFF  32768    // 4096 halves  [tile16][l32][j8] (8 KB) x + bias@d13
#define W1_OFF  40960    // 4096 halves  [tile4][kt2][lane64][j8] (8 KB)
#define W2_OFF  49152    // 1024 halves  [kt2][lane64][j8] (2 KB)

#define LOG2E 1.44269504088896340736f
#define TWO_LOG2E 2.88539008177792681472f

// gate row r in [0,256): class r>>6 in {i,f,g,o}; g scaled +2*log2e
// (tanh via e^{2g}), i/f/o scaled -log2e (sigmoid via e^{-v}).
__device__ __forceinline__ float gate_scale(int r) {
  return ((r >> 6) == 2) ? TWO_LOG2E : -LOG2E;
}

__device__ __forceinline__ f32x2 vexp2(f32x2 v) {
  f32x2 r;
  r[0] = __builtin_amdgcn_exp2f(v[0]);
  r[1] = __builtin_amdgcn_exp2f(v[1]);
  return r;
}
__device__ __forceinline__ f32x2 vrcp(f32x2 v) {
  f32x2 r;
  r[0] = __builtin_amdgcn_rcpf(v[0]);
  r[1] = __builtin_amdgcn_rcpf(v[1]);
  return r;
}

// RTE f32 pair -> packed 2xfp16 in a u32
__device__ __forceinline__ unsigned pack2(float a, float b) {
  unsigned lo = (unsigned)__builtin_bit_cast(unsigned short, (_Float16)a);
  unsigned hi = (unsigned)__builtin_bit_cast(unsigned short, (_Float16)b);
  return lo | (hi << 16);
}

__global__ void prep_kernel(const float* __restrict__ W_ih,
                            const float* __restrict__ W_hh,
                            const float* __restrict__ b_ih,
                            const float* __restrict__ b_hh,
                            const float* __restrict__ W1,
                            const float* __restrict__ W2,
                            _Float16* __restrict__ whh,
                            _Float16* __restrict__ wx,
                            _Float16* __restrict__ w1,
                            _Float16* __restrict__ w2) {
  int idx = blockIdx.x * 256 + threadIdx.x;
  if (idx < 16384) {  // whh A-frags: row = gate, k = h-dim
    int tile = idx >> 10, r = idx & 1023;
    int kt = r >> 9, l = (r >> 3) & 63, j = idx & 7;
    int row = tile * 16 + (l & 15);
    int k = kt * 32 + ((l >> 4) << 3) + j;
    whh[idx] = (_Float16)(W_hh[row * 64 + k] * gate_scale(row));
  }
  if (idx < 4096) {   // wx A-frags: d<13: W_ih; d==13: bias; else 0
    int tile = idx >> 8, l32 = (idx >> 3) & 31, j = idx & 7;
    int row = tile * 16 + (l32 & 15);
    int d = ((l32 >> 4) << 3) + j;  // 0..15
    float v = 0.f;
    if (d < NI) v = W_ih[row * NI + d] * gate_scale(row);
    else if (d == NI) v = (b_ih[row] + b_hh[row]) * gate_scale(row);
    wx[idx] = (_Float16)v;
  }
  if (idx < 4096) {   // W1 A-frags: row = z-dim, k = h-dim
    int tile = idx >> 10, r = idx & 1023;
    int kt = r >> 9, l = (r >> 3) & 63, j = idx & 7;
    int row = tile * 16 + (l & 15);
    int k = kt * 32 + ((l >> 4) << 3) + j;
    w1[idx] = (_Float16)W1[row * 64 + k];
  }
  if (idx < 1024) {   // W2 A-frags: row = out-dim (>=13 zero)
    int kt = idx >> 9, l = (idx >> 3) & 63, j = idx & 7;
    int row = l & 15;
    int k = kt * 32 + ((l >> 4) << 3) + j;
    w2[idx] = (_Float16)((row < 13) ? W2[row * 64 + k] : 0.f);
  }
}

// k-regroup: producer lane (qp,mcol) holds packed pairs hpk[a][p] for
// hcol = 16a + 4qp + 2p + u. Consumer B-frag slot s of kt wants
// hdim = 32kt + 8q + 2s + u. -> a_src = 2kt + (q>>1), pair = s&1,
// q_src = (2q + (s>>1)) & 3. Two bpermutes (a_src reg choice) + cndmask.
__device__ __forceinline__ void exchange4(const unsigned pk[4][2], int idxE,
                                          int idxO, bool hihalf, half8 out[2]) {
#pragma unroll
  for (int kt = 0; kt < 2; ++kt) {
    union { unsigned u[4]; half8 h; } c;
#pragma unroll
    for (int s = 0; s < 4; ++s) {
      const int pidx = s & 1;
      const int ix = (s >> 1) ? idxO : idxE;
      unsigned lo = (unsigned)__builtin_amdgcn_ds_bpermute(ix, (int)pk[2 * kt][pidx]);
      unsigned hi = (unsigned)__builtin_amdgcn_ds_bpermute(ix, (int)pk[2 * kt + 1][pidx]);
      c.u[s] = hihalf ? hi : lo;
    }
    out[kt] = c.h;
  }
}

__global__ __launch_bounds__(256, 4)
void lstm_mfma(const float* __restrict__ x,
               const _Float16* __restrict__ wm_g,   // whh + wx, 40 KB contiguous
               const _Float16* __restrict__ w1_g,
               const _Float16* __restrict__ w2_g,
               const float* __restrict__ b1v,
               const float* __restrict__ b2v,
               float* __restrict__ out) {
  __shared__ __attribute__((aligned(16))) _Float16 wlds[20480];  // 40 KB

  const int tid = threadIdx.x;
  const int wave = tid >> 6;
  const int lane = tid & 63;
  const int quad = lane >> 4;
  const int mcol = lane & 15;
  const int row0 = blockIdx.x * 128 + wave * 32;

  // stage weights (one-time, coalesced 16B)
  {
    const f32x4* __restrict__ s = (const f32x4*)wm_g;
    f32x4* d = (f32x4*)wlds;
#pragma unroll
    for (int i = 0; i < 10; ++i) d[tid + 256 * i] = s[tid + 256 * i];
  }
  __syncthreads();

  const half8* __restrict__ whha = (const half8*)wlds;            // (tile*2+kt)*64+lane
  const half8* __restrict__ wxa  = (const half8*)(wlds + 16384);  // tile*32+(lane&31)

  const int idxE = ((((quad << 1)) & 3) * 16 + mcol) << 2;
  const int idxO = ((((quad << 1) | 1) & 3) * 16 + mcol) << 2;
  const bool hihalf = lane >= 32;

  const f32x4 ZERO4 = {0.f, 0.f, 0.f, 0.f};

  f32x2 c_st[2][4][2];  // [bt][a][pair]
#pragma unroll
  for (int bt = 0; bt < 2; ++bt)
#pragma unroll
    for (int a = 0; a < 4; ++a)
#pragma unroll
      for (int p = 0; p < 2; ++p) { c_st[bt][a][p][0] = 0.f; c_st[bt][a][p][1] = 0.f; }

  half8 hb[2][2];        // [bt][kt] h^T B-frags (valid from t=1)
  unsigned hpk[2][4][2]; // [bt][a][pair] packed h fp16

#pragma unroll 1
  for (int t = 0; t < TT; ++t) {
    // x^T B-frags for the k=64..95 band: q0: x0-7; q1: x8-12, 1.0, 0, 0; q2,3: 0
    half8 xb[2];
#pragma unroll
    for (int bt = 0; bt < 2; ++bt) {
      const float* __restrict__ xp =
          x + (size_t)(row0 + bt * 16 + mcol) * (TT * NI) + t * NI;
      half8 v;
#pragma unroll
      for (int j = 0; j < 8; ++j) v[j] = (_Float16)0.f;
      if (quad == 0) {
        float lo[4], hi[4];
        __builtin_memcpy(lo, xp, 16);
        __builtin_memcpy(hi, xp + 4, 16);
#pragma unroll
        for (int j = 0; j < 4; ++j) { v[j] = (_Float16)lo[j]; v[4 + j] = (_Float16)hi[j]; }
      } else if (quad == 1) {
        float lo[4];
        __builtin_memcpy(lo, xp + 8, 16);
#pragma unroll
        for (int j = 0; j < 4; ++j) v[j] = (_Float16)lo[j];
        v[4] = (_Float16)xp[12];
        v[5] = (_Float16)1.0f;  // bias channel k=77
      }
      xb[bt] = v;
    }

#pragma unroll
    for (int a = 0; a < 4; ++a) {   // h-col group: hcols 16a..16a+15
      f32x4 acc[4][2];  // [gate-class][bt]; D row = gate, col = batch
      // x+bias band (A lanes q2,3 alias q0,1 -> B-side zeros cover)
#pragma unroll
      for (int g = 0; g < 4; ++g) {
        const half8 wx8 = wxa[(g * 4 + a) * 32 + (lane & 31)];
        acc[g][0] = __builtin_amdgcn_mfma_f32_16x16x32_f16(wx8, xb[0], ZERO4, 0, 0, 0);
        acc[g][1] = __builtin_amdgcn_mfma_f32_16x16x32_f16(wx8, xb[1], ZERO4, 0, 0, 0);
      }
      if (t > 0) {
#pragma unroll
        for (int kt = 0; kt < 2; ++kt)
#pragma unroll
          for (int g = 0; g < 4; ++g) {
            const half8 wh = whha[((g * 4 + a) * 2 + kt) * 64 + lane];
            acc[g][0] = __builtin_amdgcn_mfma_f32_16x16x32_f16(wh, hb[0][kt], acc[g][0], 0, 0, 0);
            acc[g][1] = __builtin_amdgcn_mfma_f32_16x16x32_f16(wh, hb[1][kt], acc[g][1], 0, 0, 0);
          }
      }
      // elementwise: lane owns hcol = 16a + 4*quad + reg, batch = 16bt + mcol
#pragma unroll
      for (int bt = 0; bt < 2; ++bt)
#pragma unroll
        for (int p = 0; p < 2; ++p) {
          f32x2 si = {acc[0][bt][2 * p], acc[0][bt][2 * p + 1]};
          f32x2 sf = {acc[1][bt][2 * p], acc[1][bt][2 * p + 1]};
          f32x2 sg = {acc[2][bt][2 * p], acc[2][bt][2 * p + 1]};
          f32x2 so = {acc[3][bt][2 * p], acc[3][bt][2 * p + 1]};
          const f32x2 A  = vexp2(sf);   // e^{-f}
          const f32x2 Bv = vexp2(si);   // e^{-i}
          const f32x2 E  = vexp2(sg);   // e^{2g}
          const f32x2 pA = 1.f + A;
          const f32x2 pB = 1.f + Bv;
          const f32x2 ep = E + 1.f;
          const f32x2 em = E - 1.f;
          const f32x2 m1 = pB * ep;
          f32x2 cv = c_st[bt][a][p];
          const f32x2 num = cv * m1 + em * pA;
          cv = num * vrcp(pA * m1);
          c_st[bt][a][p] = cv;
          const f32x2 C2 = vexp2(so);               // e^{-o}
          const f32x2 F  = vexp2(cv * TWO_LOG2E);   // e^{2c}
          const f32x2 hn = (F - 1.f) * vrcp((1.f + C2) * (F + 1.f));
          hpk[bt][a][p] = pack2(hn[0], hn[1]);
        }
    }
    // regroup h into next-t B-frags (also feeds the head after t=4)
    exchange4(hpk[0], idxE, idxO, hihalf, hb[0]);
    exchange4(hpk[1], idxE, idxO, hihalf, hb[1]);
  }

  // ---- head: z^T = relu(W1 h^T + b1) ----
  f32x4 zacc[4][2];
#pragma unroll
  for (int mz = 0; mz < 4; ++mz) {
    const f32x4 b = *(const f32x4*)(b1v + mz * 16 + quad * 4);
    zacc[mz][0] = b;
    zacc[mz][1] = b;
  }
#pragma unroll
  for (int kt = 0; kt < 2; ++kt)
#pragma unroll
    for (int mz = 0; mz < 4; ++mz) {
      const half8 wf = ((const half8*)w1_g)[(mz * 2 + kt) * 64 + lane];
      zacc[mz][0] = __builtin_amdgcn_mfma_f32_16x16x32_f16(wf, hb[0][kt], zacc[mz][0], 0, 0, 0);
      zacc[mz][1] = __builtin_amdgcn_mfma_f32_16x16x32_f16(wf, hb[1][kt], zacc[mz][1], 0, 0, 0);
    }
  unsigned zpk[2][4][2];
#pragma unroll
  for (int bt = 0; bt < 2; ++bt)
#pragma unroll
    for (int mz = 0; mz < 4; ++mz)
#pragma unroll
      for (int p = 0; p < 2; ++p)
        zpk[bt][mz][p] = pack2(fmaxf(zacc[mz][bt][2 * p], 0.f),
                               fmaxf(zacc[mz][bt][2 * p + 1], 0.f));
  half8 zb[2][2];
  exchange4(zpk[0], idxE, idxO, hihalf, zb[0]);
  exchange4(zpk[1], idxE, idxO, hihalf, zb[1]);

  // ---- head: out^T = W2 z^T + b2 ----
  f32x4 oacc[2];
  {
    f32x4 b;
    if (quad < 3) {
      b = *(const f32x4*)(b2v + quad * 4);
    } else {
      b[0] = b2v[12]; b[1] = 0.f; b[2] = 0.f; b[3] = 0.f;
    }
    oacc[0] = b;
    oacc[1] = b;
  }
#pragma unroll
  for (int kt = 0; kt < 2; ++kt) {
    const half8 wf = ((const half8*)w2_g)[kt * 64 + lane];
    oacc[0] = __builtin_amdgcn_mfma_f32_16x16x32_f16(wf, zb[0][kt], oacc[0], 0, 0, 0);
    oacc[1] = __builtin_amdgcn_mfma_f32_16x16x32_f16(wf, zb[1][kt], oacc[1], 0, 0, 0);
  }
#pragma unroll
  for (int bt = 0; bt < 2; ++bt) {
    const int obase = (row0 + bt * 16 + mcol) * 13;
#pragma unroll
    for (int reg = 0; reg < 4; ++reg) {
      const int o = quad * 4 + reg;
      if (o < 13) out[obase + o] = oacc[bt][reg];
    }
  }
}

extern "C" void kernel_launch(void* const* d_in, const int* in_sizes, int n_in,
                              void* d_out, int out_size, void* d_ws, size_t ws_size,
                              hipStream_t stream) {
  const float* x    = (const float*)d_in[0];
  const float* W_ih = (const float*)d_in[1];
  const float* W_hh = (const float*)d_in[2];
  const float* b_ih = (const float*)d_in[3];
  const float* b_hh = (const float*)d_in[4];
  const float* W1   = (const float*)d_in[5];
  const float* b1   = (const float*)d_in[6];
  const float* W2   = (const float*)d_in[7];
  const float* b2   = (const float*)d_in[8];
  float* out = (float*)d_out;
  char* ws = (char*)d_ws;

  _Float16* whh = (_Float16*)(ws + WHH_OFF);
  _Float16* wx  = (_Float16*)(ws + WX_OFF);
  _Float16* w1  = (_Float16*)(ws + W1_OFF);
  _Float16* w2  = (_Float16*)(ws + W2_OFF);

  hipLaunchKernelGGL(prep_kernel, dim3(64), dim3(256), 0, stream,
                     W_ih, W_hh, b_ih, b_hh, W1, W2, whh, wx, w1, w2);

  const int B = in_sizes[0] / (TT * NI);  // 262144
  hipLaunchKernelGGL(lstm_mfma, dim3(B / 128), dim3(256), 0, stream,
                     x, (const _Float16*)(ws + WHH_OFF), w1, w2, b1, b2, out);
}

// Round 5
// 222.655 us; speedup vs baseline: 2.2164x; 2.2164x over previous
//
#include <hip/hip_runtime.h>
#include <math.h>

// LSTMNextWindowPredictor via fp16 single-product MFMA: B=262144, I=13, H=64,
// T=5, O=13, fp32 in/out. Per wave: M=32 rows. Per t:
//   G[32x256] = X_t[32x13(pad32)] @ W_ih^T + H[32x64] @ W_hh^T
// via mfma_f32_16x16x32_f16 (fp32 accumulate), then elementwise LSTM update.
// h lives per-wave in LDS as fp16 in A-fragment k-contiguous layout (XOR
// swizzled by row&7) -> A-frag loads are pure ds_read_b128, no conversion.
// R4: sigmoid/tanh via v_exp_f32 + v_rcp_f32 hardware ops.
// R6: LOG2E folded into prep-scaled weights; single-rcp fused sigmoid*tanh
// -> 7 trans ops/element (5 exp2 + 2 rcp).
// R7 lesson: unified VGPR+AGPR ~128/wave pins 4 waves/SIMD; launch_bounds
// (.,8) forces 32 VGPRs -> catastrophic scratch spill. Keep (.,4).
// R8 lesson: register-resident h + ds_bpermute exchange spills (array params
// defeat SROA) -> 1.4 GB scratch. Keep h in LDS.
// R9: 512-thread blocks -> whh(32K) + wih(8K) + hshm(8x4K=32K) = 72 KB
// <= 80 KB/block at 2 blocks/CU = 16 waves/CU: weights in LDS (conflict-free
// ds_read_b128, kills the L2-thrashed global weight path: FETCH had 85 MB/
// dispatch of HBM weight re-reads stalling every MFMA cluster) at the SAME
// occupancy R5 bought by moving them out. pk-f32 elementwise kept from R7.

#define TT 5
#define NI 13

typedef _Float16 half8 __attribute__((ext_vector_type(8)));
typedef __attribute__((ext_vector_type(4))) float f32x4;
typedef __attribute__((ext_vector_type(2))) float f32x2;

// ws byte offsets
#define WHH_OFF  0       // 16384 halves [kt2][nt16][lane64][j8]  (32 KB)
#define WIH_OFF  32768   // 4096 halves  [nt16][l32][j8] (quads 2,3 alias; A-side zeros cover)
#define W1_OFF   40960   // 4096 halves  [kt2][nt4][lane64][j8]
#define W2_OFF   49152   // 1024 halves  [kt2][lane64][j8] (n>=13 zero)
#define BIAS_OFF 51200   // 256 floats (b_ih + b_hh, gate-scaled)

#define LOG2E 1.44269504088896340736f
#define TWO_LOG2E 2.88539008177792681472f

// gate scale: n in [0,256); gate = n>>6 in {i,f,g,o}; g-gate scaled +2*log2e
// (tanh via e^{2g}), i/f/o scaled -log2e (sigmoid via e^{-v}).
__device__ __forceinline__ float gate_scale(int n) {
  return ((n >> 6) == 2) ? TWO_LOG2E : -LOG2E;
}

__device__ __forceinline__ f32x2 vexp2(f32x2 v) {
  f32x2 r;
  r[0] = __builtin_amdgcn_exp2f(v[0]);
  r[1] = __builtin_amdgcn_exp2f(v[1]);
  return r;
}
__device__ __forceinline__ f32x2 vrcp(f32x2 v) {
  f32x2 r;
  r[0] = __builtin_amdgcn_rcpf(v[0]);
  r[1] = __builtin_amdgcn_rcpf(v[1]);
  return r;
}

__global__ void prep_kernel(const float* __restrict__ W_ih,
                            const float* __restrict__ W_hh,
                            const float* __restrict__ b_ih,
                            const float* __restrict__ b_hh,
                            const float* __restrict__ W1,
                            const float* __restrict__ W2,
                            _Float16* __restrict__ whh,
                            _Float16* __restrict__ wih,
                            _Float16* __restrict__ w1,
                            _Float16* __restrict__ w2,
                            float* __restrict__ bias) {
  int idx = blockIdx.x * 256 + threadIdx.x;
  if (idx < 16384) {  // W_hh B-frags: B[k][n] = W_hh[n*64+k]
    int kt = idx >> 13, r = idx & 8191;
    int nt = r >> 9, lane = (r >> 3) & 63, j = idx & 7;
    int k = kt * 32 + ((lane >> 4) << 3) + j;
    int n = (nt << 4) + (lane & 15);
    whh[idx] = (_Float16)(W_hh[n * 64 + k] * gate_scale(n));
  }
  if (idx < 4096) {   // W_ih B-frags, k tile of 32 (k>=13 zero)
    int nt = idx >> 8, l32 = (idx >> 3) & 31, j = idx & 7;
    int k = ((l32 >> 4) << 3) + j;
    int n = (nt << 4) + (l32 & 15);
    wih[idx] = (_Float16)((k < NI) ? W_ih[n * NI + k] * gate_scale(n) : 0.f);
  }
  if (idx < 4096) {   // W1 B-frags: B[k][n] = W1[n*64+k]
    int kt = idx >> 11, r = idx & 2047;
    int nt = r >> 9, lane = (r >> 3) & 63, j = idx & 7;
    int k = kt * 32 + ((lane >> 4) << 3) + j;
    int n = (nt << 4) + (lane & 15);
    w1[idx] = (_Float16)W1[n * 64 + k];
  }
  if (idx < 1024) {   // W2 B-frags (n>=13 zero)
    int kt = idx >> 9, lane = (idx >> 3) & 63, j = idx & 7;
    int k = kt * 32 + ((lane >> 4) << 3) + j;
    int n = lane & 15;
    w2[idx] = (_Float16)((n < 13) ? W2[n * 64 + k] : 0.f);
  }
  if (idx < 256) bias[idx] = (b_ih[idx] + b_hh[idx]) * gate_scale(idx);
}

// Read A-fragments (rows mt*16+mcol, k = kt*32+quad*8+j) from swizzled fp16 LDS.
__device__ __forceinline__ void read_afrags(const _Float16* __restrict__ hw,
                                            int quad, int mcol, half8 a[2][2]) {
#pragma unroll
  for (int mt = 0; mt < 2; ++mt) {
    const int r = mt * 16 + mcol;
#pragma unroll
    for (int kt = 0; kt < 2; ++kt) {
      const int blk = (kt * 4 + quad) ^ (r & 7);
      a[mt][kt] = *(const half8*)&hw[r * 64 + blk * 8];
    }
  }
}

__global__ __launch_bounds__(512, 4)
void lstm_mfma(const float* __restrict__ x,
               const _Float16* __restrict__ wm_g,   // whh + wih contiguous 40 KB
               const _Float16* __restrict__ w1_g,
               const _Float16* __restrict__ w2_g,
               const float* __restrict__ biasp,
               const float* __restrict__ b1v,
               const float* __restrict__ b2v,
               float* __restrict__ out) {
  __shared__ __attribute__((aligned(16))) _Float16 wlds[20480];     // 40 KB: whh+wih
  __shared__ __attribute__((aligned(16))) _Float16 hshm[8][2048];   // 32 KB

  const int tid = threadIdx.x;
  const int wave = tid >> 6;
  const int lane = tid & 63;
  const int quad = lane >> 4;
  const int mcol = lane & 15;
  _Float16* __restrict__ hw = &hshm[wave][0];
  const int row0 = blockIdx.x * 256 + wave * 32;

  // stage whh+wih fragment tables into LDS (one-time, coalesced 16B)
  {
    const f32x4* __restrict__ s = (const f32x4*)wm_g;
    f32x4* d = (f32x4*)wlds;
#pragma unroll
    for (int i = 0; i < 5; ++i) d[tid + 512 * i] = s[tid + 512 * i];
  }
  __syncthreads();

  f32x2 c_st[2][4][2];  // [mt][jt][regpair]
#pragma unroll
  for (int mt = 0; mt < 2; ++mt)
#pragma unroll
    for (int jt = 0; jt < 4; ++jt)
#pragma unroll
      for (int p = 0; p < 2; ++p) { c_st[mt][jt][p][0] = 0.f; c_st[mt][jt][p][1] = 0.f; }

  float bias_r[4][4];  // [g][jt]: per-lane col = (g*4+jt)*16 + mcol
#pragma unroll
  for (int g = 0; g < 4; ++g)
#pragma unroll
    for (int jt = 0; jt < 4; ++jt)
      bias_r[g][jt] = biasp[((g * 4 + jt) << 4) + mcol];

  const half8* __restrict__ whhf = (const half8*)wlds;             // (kt*16+g*4+jt)*64+lane
  const half8* __restrict__ wihf = (const half8*)(wlds + 16384);   // (g*4+jt)*32+(lane&31)

#pragma unroll 1
  for (int t = 0; t < TT; ++t) {
    // x A-fragments (k = quad*8+j). Only quads 0,1 carry data (I=13 < 16);
    // quads 2,3 are constant zero -> no loads, no selects.
    half8 xa[2];
#pragma unroll
    for (int mt = 0; mt < 2; ++mt) {
      const float* __restrict__ xp =
          x + (size_t)(row0 + mt * 16 + mcol) * (TT * NI) + t * NI;
      half8 v;
#pragma unroll
      for (int j = 0; j < 8; ++j) v[j] = (_Float16)0.f;
      if (quad == 0) {
        float lo[4], hi[4];
        __builtin_memcpy(lo, xp, 16);
        __builtin_memcpy(hi, xp + 4, 16);
#pragma unroll
        for (int j = 0; j < 4; ++j) {
          v[j] = (_Float16)lo[j];
          v[4 + j] = (_Float16)hi[j];
        }
      } else if (quad == 1) {
        float lo[4];
        __builtin_memcpy(lo, xp + 8, 16);
        const float e12 = xp[12];
#pragma unroll
        for (int j = 0; j < 4; ++j) v[j] = (_Float16)lo[j];
        v[4] = (_Float16)e12;
      }
      xa[mt] = v;
    }

    half8 ah[2][2];
    if (t > 0) read_afrags(hw, quad, mcol, ah);

#pragma unroll 1
    for (int jt = 0; jt < 4; ++jt) {
      f32x4 acc[2][4];
#pragma unroll
      for (int mt = 0; mt < 2; ++mt)
#pragma unroll
        for (int g = 0; g < 4; ++g) {
          const float b = bias_r[g][jt];
          f32x4 z = {b, b, b, b};
          acc[mt][g] = z;
        }

      // x @ W_ih^T (scaled), B-frags from LDS
#pragma unroll
      for (int g = 0; g < 4; ++g) {
        const half8 bfr = wihf[(g * 4 + jt) * 32 + (lane & 31)];
#pragma unroll
        for (int mt = 0; mt < 2; ++mt)
          acc[mt][g] = __builtin_amdgcn_mfma_f32_16x16x32_f16(xa[mt], bfr, acc[mt][g], 0, 0, 0);
      }

      // h @ W_hh^T (h==0 at t=0), B-frags from LDS
      if (t > 0) {
#pragma unroll
        for (int kt = 0; kt < 2; ++kt)
#pragma unroll
          for (int g = 0; g < 4; ++g) {
            const half8 bfr = whhf[(kt * 16 + g * 4 + jt) * 64 + lane];
#pragma unroll
            for (int mt = 0; mt < 2; ++mt)
              acc[mt][g] = __builtin_amdgcn_mfma_f32_16x16x32_f16(ah[mt][kt], bfr, acc[mt][g], 0, 0, 0);
          }
      }

      // elementwise LSTM update over reg-pairs (v_pk_*_f32); lane owns rows
      // quad*4+reg, col jt*16+mcol. accs pre-scaled: si=-log2e*i, sf=-log2e*f,
      // sg=2log2e*g, so=-log2e*o
#pragma unroll
      for (int mt = 0; mt < 2; ++mt)
#pragma unroll
        for (int p = 0; p < 2; ++p) {
          f32x2 si = {acc[mt][0][p * 2], acc[mt][0][p * 2 + 1]};
          f32x2 sf = {acc[mt][1][p * 2], acc[mt][1][p * 2 + 1]};
          f32x2 sg = {acc[mt][2][p * 2], acc[mt][2][p * 2 + 1]};
          f32x2 so = {acc[mt][3][p * 2], acc[mt][3][p * 2 + 1]};
          const f32x2 A  = vexp2(sf);   // e^{-f}
          const f32x2 Bv = vexp2(si);   // e^{-i}
          const f32x2 E  = vexp2(sg);   // e^{2g}
          const f32x2 pA = 1.f + A;
          const f32x2 pB = 1.f + Bv;
          const f32x2 ep = E + 1.f;
          const f32x2 em = E - 1.f;
          const f32x2 m1 = pB * ep;
          f32x2 cv = c_st[mt][jt][p];
          const f32x2 num = cv * m1 + em * pA;   // contracts to v_pk_fma_f32
          cv = num * vrcp(pA * m1);
          c_st[mt][jt][p] = cv;
          const f32x2 C2 = vexp2(so);               // e^{-o}
          const f32x2 F  = vexp2(cv * TWO_LOG2E);   // e^{2c}
          const f32x2 hn = (F - 1.f) * vrcp((1.f + C2) * (F + 1.f));
#pragma unroll
          for (int u = 0; u < 2; ++u) {
            const int r = mt * 16 + quad * 4 + p * 2 + u;
            const int k = jt * 16 + mcol;
            hw[r * 64 + (((k >> 3) ^ (r & 7)) << 3) + (k & 7)] = (_Float16)hn[u];
          }
        }
    }
  }

  // ---- head: z = relu(h @ W1^T + b1), fp16 round-trip through LDS ----
  {
    half8 ah[2][2];
    read_afrags(hw, quad, mcol, ah);

    f32x4 zacc[2][4];
#pragma unroll
    for (int nt = 0; nt < 4; ++nt) {
      const float b = b1v[nt * 16 + mcol];
#pragma unroll
      for (int mt = 0; mt < 2; ++mt) {
        f32x4 z = {b, b, b, b};
        zacc[mt][nt] = z;
      }
    }
#pragma unroll
    for (int kt = 0; kt < 2; ++kt)
#pragma unroll
      for (int nt = 0; nt < 4; ++nt) {
        const half8 bfr = ((const half8*)w1_g)[(kt * 4 + nt) * 64 + lane];
#pragma unroll
        for (int mt = 0; mt < 2; ++mt)
          zacc[mt][nt] = __builtin_amdgcn_mfma_f32_16x16x32_f16(ah[mt][kt], bfr, zacc[mt][nt], 0, 0, 0);
      }
#pragma unroll
    for (int mt = 0; mt < 2; ++mt)
#pragma unroll
      for (int nt = 0; nt < 4; ++nt)
#pragma unroll
        for (int reg = 0; reg < 4; ++reg) {
          const float zv = fmaxf(zacc[mt][nt][reg], 0.f);
          const int r = mt * 16 + quad * 4 + reg;
          const int k = nt * 16 + mcol;
          hw[r * 64 + (((k >> 3) ^ (r & 7)) << 3) + (k & 7)] = (_Float16)zv;
        }
  }

  // ---- head: out = z @ W2^T + b2 ----
  {
    half8 zh[2][2];
    read_afrags(hw, quad, mcol, zh);

    const float b2r = (mcol < 13) ? b2v[mcol] : 0.f;
    f32x4 oacc[2];
#pragma unroll
    for (int mt = 0; mt < 2; ++mt) {
      f32x4 z = {b2r, b2r, b2r, b2r};
      oacc[mt] = z;
    }
#pragma unroll
    for (int kt = 0; kt < 2; ++kt) {
      const half8 bfr = ((const half8*)w2_g)[kt * 64 + lane];
#pragma unroll
      for (int mt = 0; mt < 2; ++mt)
        oacc[mt] = __builtin_amdgcn_mfma_f32_16x16x32_f16(zh[mt][kt], bfr, oacc[mt], 0, 0, 0);
    }
    if (mcol < 13) {
#pragma unroll
      for (int mt = 0; mt < 2; ++mt)
#pragma unroll
        for (int reg = 0; reg < 4; ++reg) {
          const int row = row0 + mt * 16 + quad * 4 + reg;
          out[row * 13 + mcol] = oacc[mt][reg];
        }
    }
  }
}

extern "C" void kernel_launch(void* const* d_in, const int* in_sizes, int n_in,
                              void* d_out, int out_size, void* d_ws, size_t ws_size,
                              hipStream_t stream) {
  const float* x    = (const float*)d_in[0];
  const float* W_ih = (const float*)d_in[1];
  const float* W_hh = (const float*)d_in[2];
  const float* b_ih = (const float*)d_in[3];
  const float* b_hh = (const float*)d_in[4];
  const float* W1   = (const float*)d_in[5];
  const float* b1   = (const float*)d_in[6];
  const float* W2   = (const float*)d_in[7];
  const float* b2   = (const float*)d_in[8];
  float* out = (float*)d_out;
  char* ws = (char*)d_ws;

  _Float16* whh = (_Float16*)(ws + WHH_OFF);
  _Float16* wih = (_Float16*)(ws + WIH_OFF);
  _Float16* w1  = (_Float16*)(ws + W1_OFF);
  _Float16* w2  = (_Float16*)(ws + W2_OFF);
  float* bias   = (float*)(ws + BIAS_OFF);

  hipLaunchKernelGGL(prep_kernel, dim3(64), dim3(256), 0, stream,
                     W_ih, W_hh, b_ih, b_hh, W1, W2, whh, wih, w1, w2, bias);

  const int B = in_sizes[0] / (TT * NI);  // 262144
  hipLaunchKernelGGL(lstm_mfma, dim3(B / 256), dim3(512), 0, stream,
                     x, whh, w1, w2, bias, b1, b2, out);
}